// Round 6
// baseline (175.482 us; speedup 1.0000x reference)
//
#include <hip/hip_runtime.h>

// NeuSSampler PDF importance resampling — v6: block-staged global_load_lds
// double-buffered pipeline + v4 scatter-max inversion math.
//
// v1-v5 post-mortem: VALU/ray 150-200, DS ops 0-70, divergence, launch count
// all varied — time pinned at 50-55us, HBM 26%, issue <45%. Little's law:
// waves hold loads outstanding only ~12% of lifetime (load once -> long
// LDS/cross-lane chain with zero memory in flight) -> ~0.7MB in flight vs
// ~2MB needed for BW peak. Memory is concurrency-starved, once per ray.
// v6 decouples: per block, contiguous 8-ray batches; batch k+1 streams into
// LDS via global_load_lds (no VGPR round-trip) WHILE batch k computes;
// counted vmcnt waits (2/3, never 0 mid-loop); all per-ray operand reads
// become LDS reads (2-way bank pattern = free). Each wave does 2 independent
// rays per batch (payload slots 0/1) for ILP across the one lgkm drain.
//
// Inversion math identical to v4/v5 (both passed): owner(j) = largest k with
// jf(cdf[k]) <= j via ds_max_u32 + 6-step DPP prefix-max; degenerate
// segments -> rcp(0)=inf -> NaN/inf -> fmaxf(NaN,0)=0 / fminf(inf,1)=1 ==
// reference nan_to_num + clip semantics.

#define DPP_FADD(x, ctrl, rmask)                                             \
    ((x) + __int_as_float(__builtin_amdgcn_update_dpp(                       \
               0, __float_as_int(x), (ctrl), (rmask), 0xf, true)))

__device__ __forceinline__ unsigned umax_(unsigned a, unsigned b) {
    return a > b ? a : b;
}
#define DPP_UMAX(x, ctrl, rmask)                                             \
    (umax_((x), (unsigned)__builtin_amdgcn_update_dpp(                       \
               0, (int)(x), (ctrl), (rmask), 0xf, true)))

// global -> LDS DMA, 16B/lane. LDS dest must be wave-uniform base (HW adds
// lane*16); global src is per-lane (base + lane*16 here).
__device__ __forceinline__ void gll16(const float* g, float* l) {
    __builtin_amdgcn_global_load_lds(
        (const __attribute__((address_space(1))) void*)g,
        (__attribute__((address_space(3))) void*)l, 16, 0, 0);
}

#define WAITV(n) asm volatile("s_waitcnt vmcnt(" #n ")" ::: "memory")
#define BARRIER()                                                            \
    do {                                                                     \
        asm volatile("" ::: "memory");                                       \
        __builtin_amdgcn_s_barrier();                                        \
        asm volatile("" ::: "memory");                                       \
    } while (0)

__global__ __launch_bounds__(256) void neus_sampler_kernel(
    const float* __restrict__ weights,
    const float* __restrict__ bins_g,
    const float* __restrict__ nears,
    const float* __restrict__ fars,
    float* __restrict__ out,
    int R)
{
    constexpr int NB  = 65;    // output samples per ray
    constexpr int RPB = 8;     // rays per batch
    constexpr float HPAD = 1e-5f;

    __shared__ alignas(16) float Wl[2][RPB * 128];   // 2x4096B staged weights
    __shared__ alignas(16) float Bl[2][RPB * 129];   // 2x4128B staged bins
    __shared__ float payc[4][2][128];                // SoA payloads, per wave
    __shared__ float payd[4][2][128];                //   x2 ray slots
    __shared__ float payb[4][2][128];
    __shared__ float pays[4][2][128];
    __shared__ alignas(8) unsigned best[4][2][66];

    const int lane = threadIdx.x & 63;
    const int wv   = threadIdx.x >> 6;

    const int NBt   = (R + RPB - 1) / RPB;           // total batches
    const int K     = (NBt + (int)gridDim.x - 1) / (int)gridDim.x;
    const int b0    = (int)blockIdx.x * K;
    const int bEnd  = (b0 + K < NBt) ? b0 + K : NBt;
    if (b0 >= bEnd) return;                          // block-uniform exit
    const int NFULL = R / RPB;                       // gll-stageable batches

    // first query index j with u_j >= c  (u_j = (2j+1)/130)
    auto jf = [](float c) -> int {
        int j = (int)ceilf(fmaf(65.0f, c, -0.5f));
        return j < 0 ? 0 : (j > NB ? NB : j);
    };

    // issue staging for full batch b into buffer buf (2 ops; wave 3: 3 ops)
    auto stage = [&](int b, int buf) {
        const float* gw = weights + (size_t)b * (RPB * 128) + wv * 256 + lane * 4;
        gll16(gw, &Wl[buf][wv * 256]);
        const float* gb = bins_g + (size_t)b * (RPB * 129) + wv * 256 + lane * 4;
        gll16(gb, &Bl[buf][wv * 256]);
        if (wv == 3)   // tail 4128-4096: overlap-write [3104,4128) same data
            gll16(bins_g + (size_t)b * (RPB * 129) + 776 + lane * 4,
                  &Bl[buf][776]);
    };

    // ---- v4 math: scan -> edges -> payload + scatter-max (slot-private) ----
    auto doPhase1 = [&](float2 wpair, float2 bpair, float bl,
                        float nearv, float farv, int slot) {
        if (lane < 33)   // init best[0..65]=0 (seg 0 valid default owner)
            *reinterpret_cast<unsigned long long*>(&best[wv][slot][2 * lane]) = 0ull;

        const float w1 = wpair.y + HPAD;
        float ps = (wpair.x + HPAD) + w1;
        ps = DPP_FADD(ps, 0x111, 0xf);
        ps = DPP_FADD(ps, 0x112, 0xf);
        ps = DPP_FADD(ps, 0x114, 0xf);
        ps = DPP_FADD(ps, 0x118, 0xf);
        ps = DPP_FADD(ps, 0x142, 0xa);
        ps = DPP_FADD(ps, 0x143, 0xc);

        const float total =
            __int_as_float(__builtin_amdgcn_readlane(__float_as_int(ps), 63));
        const float padding = fmaxf(1e-5f - total, 0.0f);
        const float padc    = padding * (1.0f / 128.0f);
        const float inv     = __builtin_amdgcn_rcpf(total + padding);

        const float c_hi  = fminf(1.0f, fmaf((float)(2 * lane + 2), padc, ps) * inv);
        const float c_mid = fminf(1.0f, fmaf((float)(2 * lane + 1), padc, ps - w1) * inv);
        float c_lo = __shfl_up(c_hi, 1, 64);
        if (lane == 0) c_lo = 0.0f;
        float b2 = __shfl_down(bpair.x, 1, 64);
        if (lane == 63) b2 = bl;

        const float fmn = farv - nearv;
        payc[wv][slot][2 * lane]     = c_lo;
        payc[wv][slot][2 * lane + 1] = c_mid;
        payd[wv][slot][2 * lane]     = c_mid - c_lo;
        payd[wv][slot][2 * lane + 1] = c_hi - c_mid;
        payb[wv][slot][2 * lane]     = fmaf(bpair.x, fmn, nearv);
        payb[wv][slot][2 * lane + 1] = fmaf(bpair.y, fmn, nearv);
        pays[wv][slot][2 * lane]     = (bpair.y - bpair.x) * fmn;
        pays[wv][slot][2 * lane + 1] = (b2 - bpair.y) * fmn;

        atomicMax(&best[wv][slot][jf(c_lo)],  (unsigned)(2 * lane));
        atomicMax(&best[wv][slot][jf(c_mid)], (unsigned)(2 * lane + 1));
    };

    auto doPhase2 = [&](int uray, int slot) {
        unsigned m = best[wv][slot][lane];
        m = DPP_UMAX(m, 0x111, 0xf);
        m = DPP_UMAX(m, 0x112, 0xf);
        m = DPP_UMAX(m, 0x114, 0xf);
        m = DPP_UMAX(m, 0x118, 0xf);
        m = DPP_UMAX(m, 0x142, 0xa);
        m = DPP_UMAX(m, 0x143, 0xc);

        float* const orow = out + (size_t)uray * NB;
        const float px = payc[wv][slot][m], py = payd[wv][slot][m];
        const float pz = payb[wv][slot][m], pw = pays[wv][slot][m];
        const float u  = (float)(2 * lane + 1) * (1.0f / 130.0f);
        const float t  = (u - px) * __builtin_amdgcn_rcpf(py);
        const float tc = fminf(fmaxf(t, 0.0f), 1.0f);    // NaN-safe -> 0
        orow[lane] = fmaf(tc, pw, pz);
        if (lane == 63) {
            const unsigned m64 = umax_(m, best[wv][slot][64]);
            const float qx = payc[wv][slot][m64], qy = payd[wv][slot][m64];
            const float qz = payb[wv][slot][m64], qw = pays[wv][slot][m64];
            const float t2  = (129.0f / 130.0f - qx) * __builtin_amdgcn_rcpf(qy);
            const float tc2 = fminf(fmaxf(t2, 0.0f), 1.0f);
            orow[64] = fmaf(tc2, qw, qz);
        }
    };

    int buf = 0;
    if (b0 < NFULL) stage(b0, 0);                    // prologue

    for (int b = b0; b < bEnd; ++b) {
        const int nb = b + 1;
        const bool donext = (nb < bEnd) && (nb < NFULL);
        if (donext) stage(nb, buf ^ 1);              // keep pipe full FIRST

        if (b < NFULL) {
            // counted wait: batch b's loads are older than the nshare just
            // issued -> vmcnt <= nshare completes them (never drain to 0
            // mid-loop). Also drains prior phase2 stores (older still).
            if (!donext)      WAITV(0);
            else if (wv == 3) WAITV(3);
            else              WAITV(2);
            BARRIER();                               // all waves' DMA visible

            const int urA  = __builtin_amdgcn_readfirstlane(b * RPB + wv);
            const int urB  = urA + 4;
            const int rowA = wv, rowB = wv + 4;

            // operands from LDS: stride-8B lane pattern = 2 lanes/bank = free
            const float2 wA = *reinterpret_cast<const float2*>(
                &Wl[buf][rowA * 128 + 2 * lane]);
            const float bA0 = Bl[buf][rowA * 129 + 2 * lane];
            const float bA1 = Bl[buf][rowA * 129 + 2 * lane + 1];
            const float blA = Bl[buf][rowA * 129 + 128];     // broadcast
            const float2 wB = *reinterpret_cast<const float2*>(
                &Wl[buf][rowB * 128 + 2 * lane]);
            const float bB0 = Bl[buf][rowB * 129 + 2 * lane];
            const float bB1 = Bl[buf][rowB * 129 + 2 * lane + 1];
            const float blB = Bl[buf][rowB * 129 + 128];

            doPhase1(wA, make_float2(bA0, bA1), blA, nears[urA], fars[urA], 0);
            doPhase1(wB, make_float2(bB0, bB1), blB, nears[urB], fars[urB], 1);
            asm volatile("s_waitcnt lgkmcnt(0)" ::: "memory");  // one drain, 2 rays
            doPhase2(urA, 0);
            doPhase2(urB, 1);

            BARRIER();   // all waves done reading buf before it's re-staged
        } else {
            // partial tail batch (R % 8 != 0 only): direct-global v4 path
            for (int k = 0; k < 2; ++k) {
                const int rr = b * RPB + wv + 4 * k;
                if (rr < R) {
                    const int ur = __builtin_amdgcn_readfirstlane(rr);
                    const float2 wp = reinterpret_cast<const float2*>(
                        weights + (size_t)ur * 128)[lane];
                    const float* brow = bins_g + (size_t)ur * 129;
                    const float2 bp = reinterpret_cast<const float2*>(brow)[lane];
                    doPhase1(wp, bp, brow[128], nears[ur], fars[ur], k);
                    asm volatile("s_waitcnt lgkmcnt(0)" ::: "memory");
                    doPhase2(ur, k);
                }
            }
        }
        buf ^= 1;
    }
}

extern "C" void kernel_launch(void* const* d_in, const int* in_sizes, int n_in,
                              void* d_out, int out_size, void* d_ws, size_t ws_size,
                              hipStream_t stream) {
    const float* weights = (const float*)d_in[0];   // [R,128,1]
    const float* ebins   = (const float*)d_in[1];   // [R,129]
    const float* nears   = (const float*)d_in[2];   // [R,1]
    const float* fars    = (const float*)d_in[3];   // [R,1]
    float* out = (float*)d_out;                     // [R,65]
    const int R = in_sizes[0] / 128;
    const int NBt = (R + 7) / 8;                    // 8-ray batches
    int blocks = NBt < 2048 ? NBt : 2048;           // contiguous K-batch runs
    hipLaunchKernelGGL(neus_sampler_kernel, dim3(blocks), dim3(256), 0, stream,
                       weights, ebins, nears, fars, out, R);
}

// Round 7
// 163.766 us; speedup vs baseline: 1.0715x; 1.0715x over previous
//
#include <hip/hip_runtime.h>

// NeuSSampler PDF importance resampling — v7: dual-ray straight-line wave,
// all loads up front + v4 scatter-max inversion math (verified).
//
// v1-v6 model: best variants pinned at 50us, VALUBusy<=45%, HBM 26%.
// Wave lifetime ~5200cyc vs ~2000cyc critical path; loads outstanding only
// ~20% of lifetime => ~2.9 TB/s logical (Little's law). v5 (prefetch loop)
// and v6 (staged pipeline) both lost the gain to their own structure
// (register copies / barriers+occupancy). v7 is the minimal fix on top of
// v4: one wave = TWO adjacent rays, straight-line:
//   - 4 vector loads (2KB/wave, 2x v4) issued back-to-back at wave start;
//     ray B computes with zero exposed latency (its data landed under A's
//     ~900cyc compute chain)
//   - wave count halves -> per-wave cold start (kernarg s_loads) amortized
//   - ONE lgkmcnt(0) drain for both rays; phase-2's two 6-step DPP
//     prefix-max chains interleave (fills 4-cyc DPP dep bubbles)
//   - no barriers (LDS wave-private), no loop-carried copies, SoA payloads
//     (conflict-free writes), LDS 18.5KB -> still 8 blocks/CU
//
// Math identical to v4/v5/v6 (all passed): owner(j) = largest k with
// jf(cdf[k]) <= j via ds_max_u32 scatter + DPP prefix-max; degenerate
// segments -> rcp(0)=inf -> NaN/inf -> fmaxf(NaN,0)=0 / fminf(inf,1)=1
// == reference nan_to_num + clip gather semantics.

#define DPP_FADD(x, ctrl, rmask)                                             \
    ((x) + __int_as_float(__builtin_amdgcn_update_dpp(                       \
               0, __float_as_int(x), (ctrl), (rmask), 0xf, true)))

__device__ __forceinline__ unsigned umax_(unsigned a, unsigned b) {
    return a > b ? a : b;
}
#define DPP_UMAX(x, ctrl, rmask)                                             \
    (umax_((x), (unsigned)__builtin_amdgcn_update_dpp(                       \
               0, (int)(x), (ctrl), (rmask), 0xf, true)))

__global__ __launch_bounds__(256) void neus_sampler_kernel(
    const float* __restrict__ weights,
    const float* __restrict__ bins_g,
    const float* __restrict__ nears,
    const float* __restrict__ fars,
    float* __restrict__ out,
    int R)
{
    constexpr int NB = 65;    // output samples per ray
    constexpr float HPAD = 1e-5f;

    // SoA payloads, wave-private, x2 ray slots. 18.5KB/block total.
    __shared__ float payc[4][2][128];
    __shared__ float payd[4][2][128];
    __shared__ float payb[4][2][128];
    __shared__ float pays[4][2][128];
    __shared__ alignas(8) unsigned best[4][2][66];

    const int lane = threadIdx.x & 63;
    const int wv   = threadIdx.x >> 6;
    const int gw   = blockIdx.x * 4 + wv;       // global wave id
    const int rayA = gw * 2;
    if (rayA >= R) return;                      // wave-uniform
    const int urA   = __builtin_amdgcn_readfirstlane(rayA);
    const bool haveB = (rayA + 1 < R);          // wave-uniform
    const int urB   = haveB ? urA + 1 : urA;    // clamp (loads stay in-bounds)

    // ---- ALL vector loads up front: 4 x 512B in flight per wave ----
    const float2 wA = reinterpret_cast<const float2*>(weights + (size_t)urA * 128)[lane];
    const float* browA = bins_g + (size_t)urA * 129;
    const float2 bA = reinterpret_cast<const float2*>(browA)[lane];
    const float2 wB = reinterpret_cast<const float2*>(weights + (size_t)urB * 128)[lane];
    const float* browB = bins_g + (size_t)urB * 129;
    const float2 bB = reinterpret_cast<const float2*>(browB)[lane];
    // uniform -> s_loads (scalar path, don't consume vector-mem slots)
    const float blA = browA[128], blB = browB[128];
    const float nA = nears[urA], fA = fars[urA];
    const float nB = nears[urB], fB = fars[urB];

    // first query index j with u_j >= c  (u_j = (2j+1)/130)
    auto jf = [](float c) -> int {
        int j = (int)ceilf(fmaf(65.0f, c, -0.5f));
        return j < 0 ? 0 : (j > NB ? NB : j);
    };

    // ---- v4 math, phase 1: scan -> edges -> payloads + scatter-max ----
    auto doPhase1 = [&](float2 wpair, float2 bpair, float bl,
                        float nearv, float farv, int slot) {
        if (lane < 33)   // init best[0..65]=0 (segment 0 valid default owner)
            *reinterpret_cast<unsigned long long*>(&best[wv][slot][2 * lane]) = 0ull;

        const float w1 = wpair.y + HPAD;
        float ps = (wpair.x + HPAD) + w1;       // pair sum
        ps = DPP_FADD(ps, 0x111, 0xf);  // row_shr:1
        ps = DPP_FADD(ps, 0x112, 0xf);  // row_shr:2
        ps = DPP_FADD(ps, 0x114, 0xf);  // row_shr:4
        ps = DPP_FADD(ps, 0x118, 0xf);  // row_shr:8
        ps = DPP_FADD(ps, 0x142, 0xa);  // row_bcast:15 -> rows 1,3
        ps = DPP_FADD(ps, 0x143, 0xc);  // row_bcast:31 -> rows 2,3

        const float total =
            __int_as_float(__builtin_amdgcn_readlane(__float_as_int(ps), 63));
        const float padding = fmaxf(1e-5f - total, 0.0f);
        const float padc    = padding * (1.0f / 128.0f);
        const float inv     = __builtin_amdgcn_rcpf(total + padding);

        const float c_hi  = fminf(1.0f, fmaf((float)(2 * lane + 2), padc, ps) * inv);
        const float c_mid = fminf(1.0f, fmaf((float)(2 * lane + 1), padc, ps - w1) * inv);
        float c_lo = __shfl_up(c_hi, 1, 64);
        if (lane == 0) c_lo = 0.0f;             // cdf[0]
        float b2 = __shfl_down(bpair.x, 1, 64); // bins[2l+2]
        if (lane == 63) b2 = bl;                // bins[128]

        const float fmn = farv - nearv;
        payc[wv][slot][2 * lane]     = c_lo;
        payc[wv][slot][2 * lane + 1] = c_mid;
        payd[wv][slot][2 * lane]     = c_mid - c_lo;
        payd[wv][slot][2 * lane + 1] = c_hi - c_mid;
        payb[wv][slot][2 * lane]     = fmaf(bpair.x, fmn, nearv);
        payb[wv][slot][2 * lane + 1] = fmaf(bpair.y, fmn, nearv);
        pays[wv][slot][2 * lane]     = (bpair.y - bpair.x) * fmn;
        pays[wv][slot][2 * lane + 1] = (b2 - bpair.y) * fmn;

        atomicMax(&best[wv][slot][jf(c_lo)],  (unsigned)(2 * lane));
        atomicMax(&best[wv][slot][jf(c_mid)], (unsigned)(2 * lane + 1));
    };

    // ---- phase 2: prefix-max ownership + interp + coalesced store ----
    auto doPhase2 = [&](int uray, int slot) {
        unsigned m = best[wv][slot][lane];
        m = DPP_UMAX(m, 0x111, 0xf);
        m = DPP_UMAX(m, 0x112, 0xf);
        m = DPP_UMAX(m, 0x114, 0xf);
        m = DPP_UMAX(m, 0x118, 0xf);
        m = DPP_UMAX(m, 0x142, 0xa);
        m = DPP_UMAX(m, 0x143, 0xc);

        float* const orow = out + (size_t)uray * NB;
        const float px = payc[wv][slot][m], py = payd[wv][slot][m];
        const float pz = payb[wv][slot][m], pw = pays[wv][slot][m];
        const float u  = (float)(2 * lane + 1) * (1.0f / 130.0f);
        const float t  = (u - px) * __builtin_amdgcn_rcpf(py);
        const float tc = fminf(fmaxf(t, 0.0f), 1.0f);    // NaN-safe -> 0
        orow[lane] = fmaf(tc, pw, pz);
        if (lane == 63) {                                // output 64
            const unsigned m64 = umax_(m, best[wv][slot][64]);
            const float qx = payc[wv][slot][m64], qy = payd[wv][slot][m64];
            const float qz = payb[wv][slot][m64], qw = pays[wv][slot][m64];
            const float t2  = (129.0f / 130.0f - qx) * __builtin_amdgcn_rcpf(qy);
            const float tc2 = fminf(fmaxf(t2, 0.0f), 1.0f);
            orow[64] = fmaf(tc2, qw, qz);
        }
    };

    doPhase1(wA, bA, blA, nA, fA, 0);
    doPhase1(wB, bB, blB, nB, fB, 1);           // B's loads landed under A

    // one drain for both rays (atomics -> best reads); wave-private LDS,
    // same-wave DS ops are in-order => no barrier needed.
    asm volatile("s_waitcnt lgkmcnt(0)" ::: "memory");

    doPhase2(urA, 0);
    if (haveB) doPhase2(urB, 1);                // two DPP chains interleave
}

extern "C" void kernel_launch(void* const* d_in, const int* in_sizes, int n_in,
                              void* d_out, int out_size, void* d_ws, size_t ws_size,
                              hipStream_t stream) {
    const float* weights = (const float*)d_in[0];   // [R,128,1]
    const float* ebins   = (const float*)d_in[1];   // [R,129]
    const float* nears   = (const float*)d_in[2];   // [R,1]
    const float* fars    = (const float*)d_in[3];   // [R,1]
    float* out = (float*)d_out;                     // [R,65]
    const int R = in_sizes[0] / 128;
    const int waves = (R + 1) / 2;                  // 2 rays per wave
    const int blocks = (waves + 3) / 4;             // 4 waves per block
    hipLaunchKernelGGL(neus_sampler_kernel, dim3(blocks), dim3(256), 0, stream,
                       weights, ebins, nears, fars, out, R);
}